// Round 1
// baseline (265.779 us; speedup 1.0000x reference)
//
#include <hip/hip_runtime.h>
#include <cstdint>
#include <cstddef>

// ---------------- problem constants ----------------
#define T_REAL 14884        // 4*61*61 real pixels
#define TPAD   14976        // padded to 117*128 (= 234*64)
#define CDIM   256
#define HW     3721         // 61*61
#define NTILE  234          // number of 64-wide column tiles
#define NRB    117          // number of 128-wide row blocks
#define NSLICE 8

static constexpr float SCALE = 20.6099291555566f;   // log2(e)/0.07

typedef _Float16 f16x8 __attribute__((ext_vector_type(8)));
typedef float    f32x4 __attribute__((ext_vector_type(4)));

// ---------------- workspace layout (bytes) ----------------
#define OFF_FEATS 0u
#define SZ_FEATS  ((unsigned)TPAD * CDIM * 2u)          // 7,667,712
#define OFF_SUMSQ (OFF_FEATS + SZ_FEATS)                // T_REAL floats
#define OFF_LAB   (OFF_SUMSQ + 65536u)                  // TPAD ints
#define OFF_PART  (OFF_LAB + 65536u)                    // NRB*NSLICE*128*2 floats
#define SZ_PART   ((unsigned)NRB * NSLICE * 128u * 2u * 4u)
#define OFF_ACC   (OFF_PART + SZ_PART)                  // 2 floats

// ---------------- k_init: labels, padded rows, zeros ----------------
__global__ void k_init(const int* __restrict__ targets, int* __restrict__ labels,
                       _Float16* __restrict__ feats, float* __restrict__ sumsq,
                       float* __restrict__ accum) {
    int t = blockIdx.x * 256 + threadIdx.x;
    if (t == 0) { accum[0] = 0.f; accum[1] = 0.f; }
    if (t < TPAD) {
        labels[t] = (t < T_REAL) ? targets[t] : -1;
        if (t < T_REAL) {
            sumsq[t] = 0.f;
        } else {
            float4 z = make_float4(0.f, 0.f, 0.f, 0.f);
            float4* row = (float4*)(feats + (size_t)t * CDIM);
#pragma unroll
            for (int q = 0; q < 32; ++q) row[q] = z;
        }
    }
}

// ---------------- k_norm: per-pixel sum of squares (c-quarter split) ----------------
__global__ void k_norm(const float* __restrict__ emb, float* __restrict__ sumsq) {
    int hw = blockIdx.x * 256 + threadIdx.x;
    int n  = blockIdx.y, cq = blockIdx.z;
    if (hw >= HW) return;
    const float* p = emb + ((size_t)(n * CDIM + cq * 64)) * HW + hw;
    float s = 0.f;
#pragma unroll 16
    for (int c = 0; c < 64; ++c) { float v = p[(size_t)c * HW]; s += v * v; }
    atomicAdd(&sumsq[n * HW + hw], s);
}

// ---------------- k_pack: transpose (N,C,HW)->(T,C), normalize, cast fp16 ----------------
__global__ void k_pack(const float* __restrict__ emb, const float* __restrict__ sumsq,
                       _Float16* __restrict__ feats) {
    __shared__ float tile[64][65];
    int tx = threadIdx.x & 63, ty = threadIdx.x >> 6;
    int hw0 = blockIdx.x * 64, c0 = blockIdx.y * 64, n = blockIdx.z;
#pragma unroll
    for (int it = 0; it < 16; ++it) {
        int cl = it * 4 + ty;
        int hw = hw0 + tx;
        float v = 0.f;
        if (hw < HW) v = emb[((size_t)(n * CDIM + c0 + cl)) * HW + hw];
        tile[cl][tx] = v;
    }
    __syncthreads();
#pragma unroll
    for (int it = 0; it < 16; ++it) {
        int pl = it * 4 + ty;
        int hw = hw0 + pl;
        if (hw < HW) {
            int t = n * HW + hw;
            float inv = 1.f / fmaxf(sqrtf(sumsq[t]), 1e-12f);
            feats[(size_t)t * CDIM + c0 + tx] = (_Float16)(tile[tx][pl] * inv);
        }
    }
}

// ---------------- k_main: fused sim/exp/masked-rowsum ----------------
// LDS tile: 64 j-rows x 256 halves, 16B chunks XOR-swizzled: slot(j,qs) holds
// global chunk (j, qs ^ (j&7)). Staged with linear-LDS global_load_lds +
// pre-swizzled global source (rule #21).
__device__ __forceinline__ void stage_tile(const _Float16* __restrict__ feats, int jbase,
                                           _Float16* bufp, int tid) {
#pragma unroll
    for (int sweep = 0; sweep < 4; ++sweep) {
        int ch = sweep * 512 + tid;          // 0..2047 = 64 rows * 32 chunks
        int j  = ch >> 5;
        int qs = ch & 31;
        int qsrc = qs ^ (j & 7);
        const _Float16* src = feats + ((size_t)(jbase + j)) * CDIM + qsrc * 8;
        __builtin_amdgcn_global_load_lds(
            (const __attribute__((address_space(1))) void*)src,
            (__attribute__((address_space(3))) void*)(bufp + (size_t)ch * 8),
            16, 0, 0);
    }
}

__global__ __launch_bounds__(512, 4) void k_main(const _Float16* __restrict__ feats,
                                                 const int* __restrict__ labels,
                                                 float* __restrict__ partials) {
    __shared__ _Float16 buf[2][64 * 256];   // 2 x 32KB
    const int tid  = threadIdx.x;
    const int wave = tid >> 6, lane = tid & 63;
    const int il   = lane & 15, quad = lane >> 4;
    const int rb = blockIdx.x, slice = blockIdx.y;
    const int i = rb * 128 + wave * 16 + il;
    const int lab_i = labels[i];

    // B-operand (row-side) fragments held in registers for the whole kernel.
    f16x8 bfr[8];
    const _Float16* fi = feats + (size_t)i * CDIM;
#pragma unroll
    for (int ks = 0; ks < 8; ++ks)
        bfr[ks] = *reinterpret_cast<const f16x8*>(fi + ks * 32 + quad * 8);

    // precomputed swizzled ds_read offsets (halves): chunk = j16*32 + (ks^hb)*4 + qx
    const int hb = (il >> 2) & 1;
    const int qx = quad ^ (il & 3);
    int lofs[4];
#pragma unroll
    for (int jj = 0; jj < 4; ++jj) lofs[jj] = (jj * 16 + il) * 256 + qx * 8;

    float accA = 0.f, accP = 0.f;

    stage_tile(feats, slice * 64, &buf[0][0], tid);
    int cur = 0;
    for (int jt = slice; jt < NTILE; jt += NSLICE) {
        asm volatile("s_waitcnt vmcnt(0)\n\ts_barrier" ::: "memory");
        int nxt = jt + NSLICE;
        if (nxt < NTILE) stage_tile(feats, nxt * 64, &buf[cur ^ 1][0], tid);

        const _Float16* bufc = &buf[cur][0];
        f32x4 acc[4];
#pragma unroll
        for (int jj = 0; jj < 4; ++jj) acc[jj] = (f32x4){0.f, 0.f, 0.f, 0.f};

#pragma unroll
        for (int ks = 0; ks < 8; ++ks) {
            const int ksx = ks ^ hb;
#pragma unroll
            for (int jj = 0; jj < 4; ++jj) {
                f16x8 a = *reinterpret_cast<const f16x8*>(bufc + lofs[jj] + ksx * 32);
                acc[jj] = __builtin_amdgcn_mfma_f32_16x16x32_f16(a, bfr[ks], acc[jj], 0, 0, 0);
            }
        }

        const int jb = jt * 64;
#pragma unroll
        for (int jj = 0; jj < 4; ++jj) {
            const int4 lj = *reinterpret_cast<const int4*>(&labels[jb + jj * 16 + quad * 4]);
#pragma unroll
            for (int r = 0; r < 4; ++r) {
                int ljr = (r == 0) ? lj.x : (r == 1) ? lj.y : (r == 2) ? lj.z : lj.w;
                float e  = exp2f(acc[jj][r] * SCALE);
                float ev = (ljr >= 0) ? e : 0.f;
                accA += ev;
                accP += (ljr == lab_i) ? ev : 0.f;
            }
        }
        cur ^= 1;
    }

    // ||f_i||^2 from the register fragments (for the diagonal term)
    float nsq = 0.f;
#pragma unroll
    for (int ks = 0; ks < 8; ++ks)
#pragma unroll
        for (int e = 0; e < 8; ++e) { float x = (float)bfr[ks][e]; nsq += x * x; }
    nsq += __shfl_xor(nsq, 16);
    nsq += __shfl_xor(nsq, 32);

    // reduce partial sums across the 4 quad groups holding the same i
    accA += __shfl_xor(accA, 16); accA += __shfl_xor(accA, 32);
    accP += __shfl_xor(accP, 16); accP += __shfl_xor(accP, 32);

    // subtract diagonal exactly once if this slice processed the tile containing j==i
    if ((((rb * 2 + (wave >> 2)) & 7)) == slice) {
        float ed = exp2f(nsq * SCALE);
        accA -= ed; accP -= ed;
    }

    if (quad == 0) {
        int idx = ((rb * NSLICE + slice) * 128 + wave * 16 + il) * 2;
        partials[idx]     = accA;
        partials[idx + 1] = accP;
    }
}

// ---------------- k_reduce: per-row loss + global accumulate ----------------
__global__ void k_reduce(const float* __restrict__ partials, float* __restrict__ accum) {
    int rb = blockIdx.x;
    int tl = threadIdx.x;             // 0..127
    int t  = rb * 128 + tl;
    float per = 0.f, cnt = 0.f;
    if (t < T_REAL) {
        float sA = 0.f, sP = 0.f;
#pragma unroll
        for (int s = 0; s < NSLICE; ++s) {
            int idx = ((rb * NSLICE + s) * 128 + tl) * 2;
            sA += partials[idx];
            sP += partials[idx + 1];
        }
        if (sP > 0.f) {
            per = logf(sA) - logf(sP);   // = -(log(pos) - log(all))
            cnt = 1.f;
        }
    }
#pragma unroll
    for (int off = 32; off >= 1; off >>= 1) {
        per += __shfl_xor(per, off);
        cnt += __shfl_xor(cnt, off);
    }
    if ((tl & 63) == 0) { atomicAdd(&accum[0], per); atomicAdd(&accum[1], cnt); }
}

__global__ void k_final(const float* __restrict__ accum, float* __restrict__ out) {
    out[0] = accum[0] / fmaxf(accum[1], 1.0f);
}

// ---------------- launch ----------------
extern "C" void kernel_launch(void* const* d_in, const int* in_sizes, int n_in,
                              void* d_out, int out_size, void* d_ws, size_t ws_size,
                              hipStream_t stream) {
    const float* emb     = (const float*)d_in[0];
    const int*   targets = (const int*)d_in[1];
    float*       out     = (float*)d_out;
    char*        ws      = (char*)d_ws;

    _Float16* feats    = (_Float16*)(ws + OFF_FEATS);
    float*    sumsq    = (float*)(ws + OFF_SUMSQ);
    int*      labels   = (int*)(ws + OFF_LAB);
    float*    partials = (float*)(ws + OFF_PART);
    float*    accum    = (float*)(ws + OFF_ACC);

    k_init  <<<dim3(59),        dim3(256), 0, stream>>>(targets, labels, feats, sumsq, accum);
    k_norm  <<<dim3(15, 4, 4),  dim3(256), 0, stream>>>(emb, sumsq);
    k_pack  <<<dim3(59, 4, 4),  dim3(256), 0, stream>>>(emb, sumsq, feats);
    k_main  <<<dim3(NRB, NSLICE), dim3(512), 0, stream>>>(feats, labels, partials);
    k_reduce<<<dim3(NRB),       dim3(128), 0, stream>>>(partials, accum);
    k_final <<<dim3(1),         dim3(1),   0, stream>>>(accum, out);
}

// Round 2
// 226.093 us; speedup vs baseline: 1.1755x; 1.1755x over previous
//
#include <hip/hip_runtime.h>
#include <cstdint>
#include <cstddef>

// ---------------- problem constants ----------------
#define T_REAL 14884        // 4*61*61 real pixels
#define TPAD   15360        // padded to 30*512
#define CDIM   256
#define HW     3721         // 61*61
#define NRB    30           // row blocks of 512
#define NCT    240          // 64-wide column tiles
#define NSL    16           // column slices (grid.y)
#define TPS    15           // tiles per slice (240/16)
#define NPADJ  476.0f       // TPAD - T_REAL

// feats are stored pre-scaled by sqrt(log2(e)/0.07) so the MFMA output IS
// sim*log2(e)/temperature, ready for exp2 with no per-element multiply.
static constexpr float SQRT_SCALE = 4.53981598f;   // sqrt(20.6099291555566)

typedef _Float16 f16x8  __attribute__((ext_vector_type(8)));
typedef float    f32x16 __attribute__((ext_vector_type(16)));

__device__ __forceinline__ float exp2_fast(float x) {
#if __has_builtin(__builtin_amdgcn_exp2f)
    return __builtin_amdgcn_exp2f(x);
#else
    return exp2f(x);
#endif
}

// ---------------- workspace layout (bytes) ----------------
#define OFF_FEATS 0u
#define SZ_FEATS  ((unsigned)TPAD * CDIM * 2u)            // 7,864,320
#define OFF_LAB   (OFF_FEATS + SZ_FEATS)                  // TPAD ints
#define OFF_PART  (OFF_LAB + (unsigned)TPAD * 4u)         // NRB*NSL*512 float2
#define SZ_PART   ((unsigned)NRB * NSL * 512u * 8u)
#define OFF_ACC   (OFF_PART + SZ_PART)                    // 2 floats

// ---------------- k_init: labels, pad feat rows, accum ----------------
__global__ void k_init(const int* __restrict__ targets, int* __restrict__ labels,
                       _Float16* __restrict__ feats, float* __restrict__ accum) {
    int t = blockIdx.x * 256 + threadIdx.x;
    if (t == 0) { accum[0] = 0.f; accum[1] = 0.f; }
    if (t < TPAD) {
        labels[t] = (t < T_REAL) ? targets[t] : -1;
        if (t >= T_REAL) {
            float4 z = make_float4(0.f, 0.f, 0.f, 0.f);
            float4* row = (float4*)(feats + (size_t)t * CDIM);
#pragma unroll
            for (int q = 0; q < 32; ++q) row[q] = z;
        }
    }
}

// ---------------- k_prep: fused norm+transpose+scale+cast (reads emb once) ----
__global__ void k_prep(const float* __restrict__ emb, _Float16* __restrict__ feats) {
    __shared__ float tile[64][257];
    __shared__ float sspart[4][64];
    const int tid = threadIdx.x;
    const int lane = tid & 63, w = tid >> 6;      // 4 waves
    const int px0 = blockIdx.x * 64, n = blockIdx.y;
    const int hw = px0 + lane;

    float ssq = 0.f;
    // coalesced loads: wave w covers channels w, w+4, ...; ssq accumulated inline
    for (int ci = w; ci < CDIM; ci += 4) {
        float v = (hw < HW) ? emb[((size_t)(n * CDIM + ci)) * HW + hw] : 0.f;
        tile[lane][ci] = v;
        ssq += v * v;
    }
    sspart[w][lane] = ssq;
    __syncthreads();

    const int p = tid >> 2, q = tid & 3;          // pixel-in-tile, channel quarter
    float s = sspart[q][p];
    s += __shfl_xor(s, 1);
    s += __shfl_xor(s, 2);
    float inv = SQRT_SCALE / fmaxf(sqrtf(s), 1e-12f);

    const int hwp = px0 + p;
    if (hwp < HW) {
        _Float16* dst = feats + ((size_t)(n * HW + hwp)) * CDIM + q * 64;
#pragma unroll
        for (int g = 0; g < 8; ++g) {
            f16x8 o;
#pragma unroll
            for (int e = 0; e < 8; ++e) o[e] = (_Float16)(tile[p][q * 64 + g * 8 + e] * inv);
            *reinterpret_cast<f16x8*>(dst + g * 8) = o;
        }
    }
}

// ---------------- k_main staging ----------------
// LDS tile: 64 j-rows x 256 halves. Slot chunk c of row j holds global chunk
// c ^ (j&7)  (16B chunks). Linear LDS dest + pre-swizzled global source.
__device__ __forceinline__ void stage_tile(const _Float16* __restrict__ feats, int jbase,
                                           _Float16* bufp, int tid) {
#pragma unroll
    for (int sweep = 0; sweep < 4; ++sweep) {
        int ch = sweep * 512 + tid;          // 0..2047 = 64 rows * 32 chunks
        int j  = ch >> 5;
        int c  = ch & 31;
        int csrc = c ^ (j & 7);
        const _Float16* src = feats + ((size_t)(jbase + j)) * CDIM + csrc * 8;
        __builtin_amdgcn_global_load_lds(
            (const __attribute__((address_space(1))) void*)src,
            (__attribute__((address_space(3))) void*)(bufp + (size_t)ch * 8),
            16, 0, 0);
    }
}

// ---------------- k_main: fused sim/exp/masked-rowsum ----------------
// Per block: 8 waves x 64 rows = 512 rows. Per wave: B = 2 row-groups of 32
// (in registers, whole kernel), A = 64-col tile from LDS, 2x2 register tile of
// 32x32x16 MFMAs -> each A-read feeds 2 MFMAs (8 B/elem LDS intensity).
__global__ __launch_bounds__(512, 2) void k_main(const _Float16* __restrict__ feats,
                                                 const int* __restrict__ labels,
                                                 float2* __restrict__ partials) {
    __shared__ _Float16 buf[2][64 * 256];   // 2 x 32KB
    const int tid  = threadIdx.x;
    const int w    = tid >> 6, lane = tid & 63;
    const int lo   = lane & 31, hi = lane >> 5, x3 = lane & 7;
    const int rb = blockIdx.x, slice = blockIdx.y;
    const int ibase = rb * 512 + w * 64;

    const int labi0 = labels[ibase + lo];
    const int labi1 = labels[ibase + 32 + lo];

    // B fragments (i-side), 2 row-groups x 16 k-subtiles, resident all kernel.
    // 32x32x16 B layout: lane holds col = lane&31, k = (lane>>5)*8 + e.
    f16x8 b0[16], b1[16];
    {
        const f16x8* r0 = (const f16x8*)(feats + (size_t)(ibase + lo) * CDIM + hi * 8);
        const f16x8* r1 = (const f16x8*)(feats + (size_t)(ibase + 32 + lo) * CDIM + hi * 8);
#pragma unroll
        for (int k = 0; k < 16; ++k) { b0[k] = r0[k * 2]; b1[k] = r1[k * 2]; }
    }

    float accA0 = 0.f, accP0 = 0.f, accA1 = 0.f, accP1 = 0.f;
    const int rowoff = lo * 256;            // halves

    stage_tile(feats, slice * 64, &buf[0][0], tid);
    int cur = 0;
#pragma unroll 1
    for (int ti = 0; ti < TPS; ++ti) {
        const int jt = slice + ti * NSL;
        asm volatile("s_waitcnt vmcnt(0)\n\ts_barrier" ::: "memory");
        if (ti + 1 < TPS) stage_tile(feats, (jt + NSL) * 64, &buf[cur ^ 1][0], tid);

        const _Float16* bc = &buf[cur][0];
        f32x16 c00 = {0,0,0,0,0,0,0,0,0,0,0,0,0,0,0,0};
        f32x16 c01 = c00, c10 = c00, c11 = c00;

#pragma unroll
        for (int k = 0; k < 16; ++k) {
            // A layout: lane reads j-row = lane&31 (+32 for jg1), k=(lane>>5)*8+e
            // swizzled slot: global chunk g = k*2+hi lives at g ^ x3
            const int co = ((k * 2 + hi) ^ x3) * 8;     // halves
            f16x8 a0 = *reinterpret_cast<const f16x8*>(bc + rowoff + co);
            f16x8 a1 = *reinterpret_cast<const f16x8*>(bc + 8192 + rowoff + co);
            c00 = __builtin_amdgcn_mfma_f32_32x32x16_f16(a0, b0[k], c00, 0, 0, 0);
            c01 = __builtin_amdgcn_mfma_f32_32x32x16_f16(a0, b1[k], c01, 0, 0, 0);
            c10 = __builtin_amdgcn_mfma_f32_32x32x16_f16(a1, b0[k], c10, 0, 0, 0);
            c11 = __builtin_amdgcn_mfma_f32_32x32x16_f16(a1, b1[k], c11, 0, 0, 0);
        }

        // epilogue: e = exp2(acc); accA += e; accP += (lab_j==lab_i) ? e : 0
        // C/D layout: col(i) = lane&31, row(j) = (reg&3)+8*(reg>>2)+4*hi
        const int jb = jt * 64;
#pragma unroll
        for (int jg = 0; jg < 2; ++jg) {
#pragma unroll
            for (int q = 0; q < 4; ++q) {
                const int4 lj = *reinterpret_cast<const int4*>(labels + jb + jg * 32 + q * 8 + hi * 4);
#pragma unroll
                for (int r = 0; r < 4; ++r) {
                    const int ljr = (r == 0) ? lj.x : (r == 1) ? lj.y : (r == 2) ? lj.z : lj.w;
                    float e0 = exp2_fast((jg ? c10 : c00)[q * 4 + r]);
                    accA0 += e0;
                    accP0 += (ljr == labi0) ? e0 : 0.f;
                    float e1 = exp2_fast((jg ? c11 : c01)[q * 4 + r]);
                    accA1 += e1;
                    accP1 += (ljr == labi1) ? e1 : 0.f;
                }
            }
        }
        cur ^= 1;
    }

    // diagonal term: ||b_i||^2 (feats pre-scaled, so this IS sim_ii*SCALE)
    float n0 = 0.f, n1 = 0.f;
#pragma unroll
    for (int k = 0; k < 16; ++k)
#pragma unroll
        for (int e = 0; e < 8; ++e) {
            float v0 = (float)b0[k][e]; n0 += v0 * v0;
            float v1 = (float)b1[k][e]; n1 += v1 * v1;
        }
    n0 += __shfl_xor(n0, 32); n1 += __shfl_xor(n1, 32);

    // merge the two k-halves (lanes l and l^32 hold the same i)
    accA0 += __shfl_xor(accA0, 32); accP0 += __shfl_xor(accP0, 32);
    accA1 += __shfl_xor(accA1, 32); accP1 += __shfl_xor(accP1, 32);

    // subtract diagonal exactly once (owner slice of the tile containing j==i)
    if (((rb * 8 + w) & (NSL - 1)) == slice) {
        float e0 = exp2_fast(n0), e1 = exp2_fast(n1);
        accA0 -= e0; accP0 -= e0;
        accA1 -= e1; accP1 -= e1;
    }

    if (hi == 0) {
        size_t base = ((size_t)(rb * NSL + slice)) * 512 + w * 64;
        partials[base + lo]      = make_float2(accA0, accP0);
        partials[base + 32 + lo] = make_float2(accA1, accP1);
    }
}

// ---------------- k_reduce: per-row loss + global accumulate ----------------
__global__ void k_reduce(const float2* __restrict__ partials, float* __restrict__ accum) {
    const int rb = blockIdx.x;          // 30
    const int rl = threadIdx.x;         // 512
    const int t  = rb * 512 + rl;
    float sA = -NPADJ, sP = 0.f;        // pad columns contribute exp2(0)=1 each
#pragma unroll
    for (int s = 0; s < NSL; ++s) {
        float2 v = partials[((size_t)(rb * NSL + s)) * 512 + rl];
        sA += v.x; sP += v.y;
    }
    float per = 0.f, cnt = 0.f;
    if (t < T_REAL && sP > 0.f) {
        per = logf(sA) - logf(sP);      // = -(log(pos) - log(all))
        cnt = 1.f;
    }
#pragma unroll
    for (int off = 32; off >= 1; off >>= 1) {
        per += __shfl_xor(per, off);
        cnt += __shfl_xor(cnt, off);
    }
    if ((threadIdx.x & 63) == 0) { atomicAdd(&accum[0], per); atomicAdd(&accum[1], cnt); }
}

__global__ void k_final(const float* __restrict__ accum, float* __restrict__ out) {
    out[0] = accum[0] / fmaxf(accum[1], 1.0f);
}

// ---------------- launch ----------------
extern "C" void kernel_launch(void* const* d_in, const int* in_sizes, int n_in,
                              void* d_out, int out_size, void* d_ws, size_t ws_size,
                              hipStream_t stream) {
    const float* emb     = (const float*)d_in[0];
    const int*   targets = (const int*)d_in[1];
    float*       out     = (float*)d_out;
    char*        ws      = (char*)d_ws;

    _Float16* feats    = (_Float16*)(ws + OFF_FEATS);
    int*      labels   = (int*)(ws + OFF_LAB);
    float2*   partials = (float2*)(ws + OFF_PART);
    float*    accum    = (float*)(ws + OFF_ACC);

    k_init  <<<dim3(60),        dim3(256), 0, stream>>>(targets, labels, feats, accum);
    k_prep  <<<dim3(59, 4),     dim3(256), 0, stream>>>(emb, feats);
    k_main  <<<dim3(NRB, NSL),  dim3(512), 0, stream>>>(feats, labels, partials);
    k_reduce<<<dim3(NRB),       dim3(512), 0, stream>>>(partials, accum);
    k_final <<<dim3(1),         dim3(1),   0, stream>>>(accum, out);
}